// Round 1
// baseline (2964.888 us; speedup 1.0000x reference)
//
#include <hip/hip_runtime.h>
#include <hip/hip_bf16.h>

#define N_V   100000
#define N_E   100000
#define NNZ_C 800000
#define HC    128
#define H_    8
#define C_    16
#define NEG   0.2f

// float atomic max via monotone int/uint mapping.
// Works with init bytes 0xFF (int -1 / uint max): positive path atomicMax(int),
// negative path atomicMin(uint). Mixed orderings converge to true float max.
__device__ __forceinline__ void atomicMaxF(float* addr, float val) {
    int iv = __float_as_int(val);
    if (iv >= 0) atomicMax((int*)addr, iv);
    else         atomicMin((unsigned int*)addr, (unsigned int)iv);
}

// ---------------- GEMM: X0 = X @ W  (N x 128) @ (128 x 128), fp32 ----------------
__global__ __launch_bounds__(256) void gemm_k(const float* __restrict__ X,
                                              const float* __restrict__ W,
                                              float* __restrict__ X0) {
    __shared__ float4 Ws[64 * 32];   // half of W: 64 rows x 128 cols = 32 KB
    __shared__ float  Xs[8][128];    // 8 rows of X: 4 KB
    int tid  = threadIdx.x;
    int row0 = blockIdx.x * 8;

    // stage X tile (8 rows x 128) as float4
    for (int i = tid; i < 8 * 32; i += 256) {
        int r = i >> 5, c4 = i & 31;
        ((float4*)&Xs[r][0])[c4] = ((const float4*)X)[(size_t)(row0 + r) * 32 + c4];
    }

    int c4 = tid & 31;        // output col group (4 cols)
    int r  = tid >> 5;        // row within tile, 0..7
    float4 acc = {0.f, 0.f, 0.f, 0.f};

    for (int half = 0; half < 2; ++half) {
        __syncthreads();      // (a) Xs ready on first pass, (b) prev compute done before Ws overwrite
        for (int i = tid; i < 64 * 32; i += 256)
            Ws[i] = ((const float4*)W)[half * 2048 + i];
        __syncthreads();
        int kbase = half * 64;
        #pragma unroll 16
        for (int kk = 0; kk < 64; ++kk) {
            float  x = Xs[r][kbase + kk];
            float4 w = Ws[kk * 32 + c4];
            acc.x = fmaf(x, w.x, acc.x);
            acc.y = fmaf(x, w.y, acc.y);
            acc.z = fmaf(x, w.z, acc.z);
            acc.w = fmaf(x, w.w, acc.w);
        }
    }
    ((float4*)X0)[(size_t)(row0 + r) * 32 + c4] = acc;
}

// ---------------- scatter-add vertex features into hyperedges (sum + count) ----------------
__global__ __launch_bounds__(256) void agg_edge_k(const float* __restrict__ X0,
                                                  const int* __restrict__ vertex,
                                                  const int* __restrict__ edges,
                                                  float* __restrict__ Xe,
                                                  int* __restrict__ e_cnt) {
    long gid = (long)blockIdx.x * 256 + threadIdx.x;
    int e = (int)(gid >> 5);      // incidence index
    int j = (int)(gid & 31);      // float4 channel group (4*j .. 4*j+3)
    int v  = vertex[e];
    int ed = edges[e];
    float4 x = ((const float4*)X0)[(size_t)v * 32 + j];
    float* dst = Xe + (size_t)ed * HC + j * 4;
    unsafeAtomicAdd(dst + 0, x.x);
    unsafeAtomicAdd(dst + 1, x.y);
    unsafeAtomicAdd(dst + 2, x.z);
    unsafeAtomicAdd(dst + 3, x.w);
    if (j == 0) atomicAdd(&e_cnt[ed], 1);
}

// ---------------- finalize Xe (mean) + edge attention logits alpha_e ----------------
__global__ __launch_bounds__(256) void edge_att_k(float* __restrict__ Xe,
                                                  const int* __restrict__ e_cnt,
                                                  const float* __restrict__ att,
                                                  float* __restrict__ alpha_e) {
    int gid = blockIdx.x * 256 + threadIdx.x;   // = m*8 + h
    int m = gid >> 3, h = gid & 7;
    float inv = 1.0f / fmaxf((float)e_cnt[m], 1.0f);
    float4* xe = (float4*)(Xe + (size_t)m * HC + h * C_);
    const float4* at = (const float4*)(att + h * C_);
    float s = 0.f;
    #pragma unroll
    for (int q = 0; q < 4; ++q) {
        float4 x = xe[q];
        x.x *= inv; x.y *= inv; x.z *= inv; x.w *= inv;
        float4 a4 = at[q];
        s += x.x * a4.x + x.y * a4.y + x.z * a4.z + x.w * a4.w;
        xe[q] = x;               // Xe now holds the mean (needed by scatter_k)
    }
    alpha_e[gid] = s;
}

// ---------------- segment max of leaky(logit) over incidences per vertex ----------------
__global__ __launch_bounds__(256) void amax_k(const float* __restrict__ alpha_e,
                                              const int* __restrict__ vertex,
                                              const int* __restrict__ edges,
                                              float* __restrict__ amax) {
    int gid = blockIdx.x * 256 + threadIdx.x;
    int e = gid >> 3, h = gid & 7;
    int v = vertex[e], ed = edges[e];
    float a = alpha_e[ed * 8 + h];
    a = (a >= 0.f) ? a : NEG * a;
    atomicMaxF(&amax[v * 8 + h], a);
}

// ---------------- softmax denominator ----------------
__global__ __launch_bounds__(256) void denom_k(const float* __restrict__ alpha_e,
                                               const int* __restrict__ vertex,
                                               const int* __restrict__ edges,
                                               const float* __restrict__ amax,
                                               float* __restrict__ denom) {
    int gid = blockIdx.x * 256 + threadIdx.x;
    int e = gid >> 3, h = gid & 7;
    int v = vertex[e], ed = edges[e];
    float a = alpha_e[ed * 8 + h];
    a = (a >= 0.f) ? a : NEG * a;
    float ex = __expf(a - amax[v * 8 + h]);
    unsafeAtomicAdd(&denom[v * 8 + h], ex);
}

// ---------------- attention-weighted scatter back to vertices ----------------
__global__ __launch_bounds__(256) void scatter_k(const float* __restrict__ Xe,
                                                 const float* __restrict__ alpha_e,
                                                 const int* __restrict__ vertex,
                                                 const int* __restrict__ edges,
                                                 const float* __restrict__ amax,
                                                 const float* __restrict__ denom,
                                                 float* __restrict__ out) {
    long gid = (long)blockIdx.x * 256 + threadIdx.x;
    int e = (int)(gid >> 5);
    int j = (int)(gid & 31);
    int v  = vertex[e];
    int ed = edges[e];
    int h  = j >> 2;                 // 4 channels per thread, 16 channels per head
    float a = alpha_e[ed * 8 + h];
    a = (a >= 0.f) ? a : NEG * a;
    float al = __expf(a - amax[v * 8 + h]) / (denom[v * 8 + h] + 1e-16f);
    float4 x = ((const float4*)Xe)[(size_t)ed * 32 + j];
    float* dst = out + (size_t)v * HC + j * 4;
    unsafeAtomicAdd(dst + 0, x.x * al);
    unsafeAtomicAdd(dst + 1, x.y * al);
    unsafeAtomicAdd(dst + 2, x.z * al);
    unsafeAtomicAdd(dst + 3, x.w * al);
}

extern "C" void kernel_launch(void* const* d_in, const int* in_sizes, int n_in,
                              void* d_out, int out_size, void* d_ws, size_t ws_size,
                              hipStream_t stream) {
    const float* X      = (const float*)d_in[0];
    const float* W      = (const float*)d_in[1];
    const float* att    = (const float*)d_in[2];
    const int*   vertex = (const int*)d_in[3];
    const int*   edges  = (const int*)d_in[4];
    float* out = (float*)d_out;

    // workspace layout (fp32 unless noted)
    float* X0      = (float*)d_ws;                         // N*128   (51.2 MB)
    float* Xe      = X0 + (size_t)N_V * HC;                // M*128   (51.2 MB)
    int*   e_cnt   = (int*)(Xe + (size_t)N_E * HC);        // M       (0.4 MB)
    float* alpha_e = (float*)(e_cnt + N_E);                // M*8     (3.2 MB)
    float* amax    = alpha_e + (size_t)N_E * H_;           // N*8     (3.2 MB)
    float* denom   = amax + (size_t)N_V * H_;              // N*8     (3.2 MB)

    hipMemsetAsync(Xe,    0,    sizeof(float) * (size_t)N_E * HC, stream);
    hipMemsetAsync(e_cnt, 0,    sizeof(int)   * (size_t)N_E,      stream);
    hipMemsetAsync(denom, 0,    sizeof(float) * (size_t)N_V * H_, stream);
    hipMemsetAsync(amax,  0xFF, sizeof(float) * (size_t)N_V * H_, stream); // acts as -inf for atomicMaxF
    hipMemsetAsync(out,   0,    sizeof(float) * (size_t)out_size, stream);

    gemm_k    <<<N_V / 8,              256, 0, stream>>>(X, W, X0);
    agg_edge_k<<<(NNZ_C * 32) / 256,   256, 0, stream>>>(X0, vertex, edges, Xe, e_cnt);
    edge_att_k<<<(N_E * H_) / 256,     256, 0, stream>>>(Xe, e_cnt, att, alpha_e);
    amax_k    <<<(NNZ_C * H_) / 256,   256, 0, stream>>>(alpha_e, vertex, edges, amax);
    denom_k   <<<(NNZ_C * H_) / 256,   256, 0, stream>>>(alpha_e, vertex, edges, amax, denom);
    scatter_k <<<(NNZ_C * 32) / 256,   256, 0, stream>>>(Xe, alpha_e, vertex, edges, amax, denom, out);
}

// Round 2
// 505.779 us; speedup vs baseline: 5.8620x; 5.8620x over previous
//
#include <hip/hip_runtime.h>
#include <hip/hip_bf16.h>

#define N_V   100000
#define N_E   100000
#define NNZ_C 800000
#define HC    128
#define H_    8
#define C_    16
#define NEG   0.2f

// ---------------- GEMM: X0 = X @ W  (N x 128) @ (128 x 128), fp32 ----------------
__global__ __launch_bounds__(256) void gemm_k(const float* __restrict__ X,
                                              const float* __restrict__ W,
                                              float* __restrict__ X0) {
    __shared__ float4 Ws[64 * 32];   // half of W: 64 rows x 128 cols = 32 KB
    __shared__ float  Xs[8][128];    // 8 rows of X: 4 KB
    int tid  = threadIdx.x;
    int row0 = blockIdx.x * 8;

    for (int i = tid; i < 8 * 32; i += 256) {
        int r = i >> 5, c4 = i & 31;
        ((float4*)&Xs[r][0])[c4] = ((const float4*)X)[(size_t)(row0 + r) * 32 + c4];
    }

    int c4 = tid & 31;
    int r  = tid >> 5;
    float4 acc = {0.f, 0.f, 0.f, 0.f};

    for (int half = 0; half < 2; ++half) {
        __syncthreads();
        for (int i = tid; i < 64 * 32; i += 256)
            Ws[i] = ((const float4*)W)[half * 2048 + i];
        __syncthreads();
        int kbase = half * 64;
        #pragma unroll 16
        for (int kk = 0; kk < 64; ++kk) {
            float  x = Xs[r][kbase + kk];
            float4 w = Ws[kk * 32 + c4];
            acc.x = fmaf(x, w.x, acc.x);
            acc.y = fmaf(x, w.y, acc.y);
            acc.z = fmaf(x, w.z, acc.z);
            acc.w = fmaf(x, w.w, acc.w);
        }
    }
    ((float4*)X0)[(size_t)(row0 + r) * 32 + c4] = acc;
}

// ---------------- CSR build: histogram / scan / fill ----------------
__global__ __launch_bounds__(256) void hist_k(const int* __restrict__ keys, int* __restrict__ cnt) {
    int e = blockIdx.x * 256 + threadIdx.x;
    if (e < NNZ_C) atomicAdd(&cnt[keys[e]], 1);
}

// exclusive scan, step 1: per-256-block scan. off has L+1 entries (off[L]=total).
__global__ __launch_bounds__(256) void scan1_k(const int* __restrict__ cnt, int* __restrict__ off,
                                               int* __restrict__ bsum, int L) {
    __shared__ int s[256];
    int i = blockIdx.x * 256 + threadIdx.x;
    int v = (i < L) ? cnt[i] : 0;
    s[threadIdx.x] = v;
    __syncthreads();
    for (int d = 1; d < 256; d <<= 1) {
        int t = 0;
        if (threadIdx.x >= d) t = s[threadIdx.x - d];
        __syncthreads();
        if (threadIdx.x >= d) s[threadIdx.x] += t;
        __syncthreads();
    }
    if (i <= L) off[i] = s[threadIdx.x] - v;   // exclusive
    if (threadIdx.x == 255) bsum[blockIdx.x] = s[255];
}

// step 2: scan block sums in-place (nb <= 512), single block of 512 threads
__global__ __launch_bounds__(512) void scan2_k(int* __restrict__ bsum, int nb) {
    __shared__ int s[512];
    int t = threadIdx.x;
    int v = (t < nb) ? bsum[t] : 0;
    s[t] = v;
    __syncthreads();
    for (int d = 1; d < 512; d <<= 1) {
        int tv = 0;
        if (t >= d) tv = s[t - d];
        __syncthreads();
        if (t >= d) s[t] += tv;
        __syncthreads();
    }
    if (t < nb) bsum[t] = s[t] - v;            // exclusive
}

// step 3: add block offsets; also init cursor = start position
__global__ __launch_bounds__(256) void scan3_k(int* __restrict__ off, const int* __restrict__ bsum,
                                               int* __restrict__ cur, int L) {
    int i = blockIdx.x * 256 + threadIdx.x;
    if (i <= L) {
        int o = off[i] + bsum[i >> 8];
        off[i] = o;
        if (i < L) cur[i] = o;
    }
}

__global__ __launch_bounds__(256) void fill_k(const int* __restrict__ keys, const int* __restrict__ vals,
                                              int* __restrict__ cur, int* __restrict__ idx) {
    int e = blockIdx.x * 256 + threadIdx.x;
    if (e < NNZ_C) {
        int p = atomicAdd(&cur[keys[e]], 1);
        idx[p] = vals[e];
    }
}

// ---------------- edge aggregation (gather) + attention logits ----------------
// one wave (64 lanes) per hyperedge; lane handles channels 2*lane, 2*lane+1
__global__ __launch_bounds__(256) void agg_gather_k(const float* __restrict__ X0,
                                                    const int* __restrict__ e_off,
                                                    const int* __restrict__ e_idx,
                                                    const float* __restrict__ att,
                                                    float* __restrict__ Xe,
                                                    float* __restrict__ alpha_e) {
    int wave = (int)((blockIdx.x * 256 + threadIdx.x) >> 6);
    int lane = threadIdx.x & 63;
    if (wave >= N_E) return;
    int beg = e_off[wave], end = e_off[wave + 1];
    float2 acc = {0.f, 0.f};
    for (int i = beg; i < end; ++i) {
        int v = e_idx[i];
        float2 x = ((const float2*)X0)[(size_t)v * 64 + lane];
        acc.x += x.x;
        acc.y += x.y;
    }
    float inv = 1.f / fmaxf((float)(end - beg), 1.f);
    acc.x *= inv; acc.y *= inv;
    ((float2*)Xe)[(size_t)wave * 64 + lane] = acc;
    // per-head dot with att: head spans 16 channels = 8 lanes
    float2 a2 = ((const float2*)att)[lane];
    float s = acc.x * a2.x + acc.y * a2.y;
    s += __shfl_xor(s, 1);
    s += __shfl_xor(s, 2);
    s += __shfl_xor(s, 4);
    if ((lane & 7) == 0) alpha_e[wave * 8 + (lane >> 3)] = s;
}

// ---------------- per-(vertex, head) softmax stats (gather, no atomics) ----------------
__global__ __launch_bounds__(256) void softmax_k(const float* __restrict__ alpha_e,
                                                 const int* __restrict__ v_off,
                                                 const int* __restrict__ v_idx,
                                                 float* __restrict__ amax,
                                                 float* __restrict__ denom) {
    int gid = blockIdx.x * 256 + threadIdx.x;   // v*8 + h
    if (gid >= N_V * H_) return;
    int v = gid >> 3, h = gid & 7;
    int beg = v_off[v], end = v_off[v + 1];
    float m = -INFINITY;
    for (int i = beg; i < end; ++i) {
        float a = alpha_e[v_idx[i] * 8 + h];
        a = (a >= 0.f) ? a : NEG * a;
        m = fmaxf(m, a);
    }
    if (!isfinite(m)) m = 0.f;
    float d = 0.f;
    for (int i = beg; i < end; ++i) {
        float a = alpha_e[v_idx[i] * 8 + h];
        a = (a >= 0.f) ? a : NEG * a;
        d += __expf(a - m);
    }
    amax[gid] = m;
    denom[gid] = d;
}

// ---------------- attention-weighted vertex output (gather) ----------------
// one wave per vertex; lane handles channels 2*lane, 2*lane+1; head = lane>>3
__global__ __launch_bounds__(256) void out_gather_k(const float* __restrict__ Xe,
                                                    const float* __restrict__ alpha_e,
                                                    const int* __restrict__ v_off,
                                                    const int* __restrict__ v_idx,
                                                    const float* __restrict__ amax,
                                                    const float* __restrict__ denom,
                                                    float* __restrict__ out) {
    int wave = (int)((blockIdx.x * 256 + threadIdx.x) >> 6);
    int lane = threadIdx.x & 63;
    if (wave >= N_V) return;
    int h = lane >> 3;
    float m  = amax[wave * 8 + h];
    float rd = 1.f / (denom[wave * 8 + h] + 1e-16f);
    int beg = v_off[wave], end = v_off[wave + 1];
    float2 acc = {0.f, 0.f};
    for (int i = beg; i < end; ++i) {
        int ed = v_idx[i];
        float a = alpha_e[ed * 8 + h];
        a = (a >= 0.f) ? a : NEG * a;
        float al = __expf(a - m) * rd;
        float2 x = ((const float2*)Xe)[(size_t)ed * 64 + lane];
        acc.x += x.x * al;
        acc.y += x.y * al;
    }
    ((float2*)out)[(size_t)wave * 64 + lane] = acc;
}

extern "C" void kernel_launch(void* const* d_in, const int* in_sizes, int n_in,
                              void* d_out, int out_size, void* d_ws, size_t ws_size,
                              hipStream_t stream) {
    const float* X      = (const float*)d_in[0];
    const float* W      = (const float*)d_in[1];
    const float* att    = (const float*)d_in[2];
    const int*   vertex = (const int*)d_in[3];
    const int*   edges  = (const int*)d_in[4];
    float* out = (float*)d_out;

    // -------- workspace layout --------
    float* X0      = (float*)d_ws;                          // N*128 floats (51.2 MB)
    float* Xe      = X0 + (size_t)N_V * HC;                 // M*128 floats (51.2 MB)
    int*   e_off   = (int*)(Xe + (size_t)N_E * HC);         // M+1
    int*   ecnt    = e_off + (N_E + 1);                     // M (hist, then cursor)
    int*   e_idx   = ecnt + N_E;                            // NNZ
    float* alpha_e = (float*)(e_idx + NNZ_C);               // M*8
    int*   bsum    = (int*)(alpha_e + (size_t)N_E * H_);    // 512
    // overlay in X0's space (X0 is dead after agg_gather_k):
    int*   v_off   = (int*)X0;                              // N+1
    int*   vcnt    = v_off + (N_V + 1);                     // N
    int*   v_idx   = vcnt + N_V;                            // NNZ
    float* amax    = (float*)(v_idx + NNZ_C);               // N*8
    float* denom   = amax + (size_t)N_V * H_;               // N*8

    const int nbE = (N_E + 1 + 255) / 256;   // scan1 grid over L+1 elements
    const int nbV = (N_V + 1 + 255) / 256;

    // -------- edge CSR build (independent of X0/Xe) --------
    hipMemsetAsync(ecnt, 0, sizeof(int) * N_E, stream);
    hist_k <<<NNZ_C / 256, 256, 0, stream>>>(edges, ecnt);
    scan1_k<<<nbE, 256, 0, stream>>>(ecnt, e_off, bsum, N_E);
    scan2_k<<<1, 512, 0, stream>>>(bsum, nbE);
    scan3_k<<<nbE, 256, 0, stream>>>(e_off, bsum, ecnt, N_E);
    fill_k <<<NNZ_C / 256, 256, 0, stream>>>(edges, vertex, ecnt, e_idx);

    // -------- GEMM + edge aggregation --------
    gemm_k      <<<N_V / 8, 256, 0, stream>>>(X, W, X0);
    agg_gather_k<<<(N_E * 64) / 256, 256, 0, stream>>>(X0, e_off, e_idx, att, Xe, alpha_e);

    // -------- vertex CSR build (overlays dead X0) --------
    hipMemsetAsync(vcnt, 0, sizeof(int) * N_V, stream);
    hist_k <<<NNZ_C / 256, 256, 0, stream>>>(vertex, vcnt);
    scan1_k<<<nbV, 256, 0, stream>>>(vcnt, v_off, bsum, N_V);
    scan2_k<<<1, 512, 0, stream>>>(bsum, nbV);
    scan3_k<<<nbV, 256, 0, stream>>>(v_off, bsum, vcnt, N_V);
    fill_k <<<NNZ_C / 256, 256, 0, stream>>>(vertex, edges, vcnt, v_idx);

    // -------- softmax + output gather --------
    softmax_k   <<<(N_V * H_) / 256 + 1, 256, 0, stream>>>(alpha_e, v_off, v_idx, amax, denom);
    out_gather_k<<<(N_V * 64) / 256, 256, 0, stream>>>(Xe, alpha_e, v_off, v_idx, amax, denom, out);
}

// Round 3
// 432.092 us; speedup vs baseline: 6.8617x; 1.1705x over previous
//
#include <hip/hip_runtime.h>
#include <hip/hip_bf16.h>

#define N_V   100000
#define N_E   100000
#define NNZ_C 800000
#define HC    128
#define H_    8
#define C_    16
#define NEG   0.2f

typedef __attribute__((ext_vector_type(8))) short bf16x8;
typedef __attribute__((ext_vector_type(4))) float f32x4;

__device__ __forceinline__ short f2bf(float f) {
    unsigned u = __float_as_uint(f);
    unsigned r = (u + 0x7FFFu + ((u >> 16) & 1u)) >> 16;   // RNE
    return (short)r;
}

// ---------------- W transpose to bf16: Wt[c][k] = bf16(W[k][c]) ----------------
__global__ __launch_bounds__(256) void wt_k(const float* __restrict__ W, unsigned short* __restrict__ Wt) {
    int i = blockIdx.x * 256 + threadIdx.x;   // 16384 elems
    int k = i >> 7, c = i & 127;
    Wt[c * 128 + k] = (unsigned short)f2bf(W[k * 128 + c]);
}

// ---------------- MFMA GEMM: X0 = X @ W, bf16 inputs, fp32 accum ----------------
// block = 256 = 4 waves; wave handles 16 rows x 128 cols; K=128 in 4 steps of 32.
__global__ __launch_bounds__(256) void gemm_mfma_k(const float* __restrict__ X,
                                                   const unsigned short* __restrict__ Wt,
                                                   float* __restrict__ X0) {
    __shared__ unsigned long long lds[4096];   // swizzled Wt, 32 KB
    int tid = threadIdx.x;
    const unsigned long long* wt8 = (const unsigned long long*)Wt;
    for (int u = tid; u < 4096; u += 256) {
        int col = u >> 5, g = u & 31;
        lds[(col << 5) | (g ^ (col & 15))] = wt8[u];   // XOR swizzle on 8B units
    }
    __syncthreads();

    int wave = tid >> 6, lane = tid & 63;
    int cl = lane & 15, kq = lane >> 4;
    int base = blockIdx.x * 64 + wave * 16;
    int rowA = base + cl;
    int srcRow = (rowA < N_V) ? rowA : (N_V - 1);

    f32x4 acc[8] = {};
    const float4* X4 = (const float4*)X;

    #pragma unroll
    for (int ks = 0; ks < 4; ++ks) {
        // A fragment: elems 0-3 at k = 32ks + 4kq + j, elems 4-7 at +16
        float4 a0 = X4[(size_t)srcRow * 32 + 8 * ks + kq];
        float4 a1 = X4[(size_t)srcRow * 32 + 8 * ks + 4 + kq];
        bf16x8 af;
        af[0] = f2bf(a0.x); af[1] = f2bf(a0.y); af[2] = f2bf(a0.z); af[3] = f2bf(a0.w);
        af[4] = f2bf(a1.x); af[5] = f2bf(a1.y); af[6] = f2bf(a1.z); af[7] = f2bf(a1.w);
        int g0 = 8 * ks + kq;       // 8B-group index of first k-half
        int g1 = g0 + 4;            // second k-half
        #pragma unroll
        for (int ct = 0; ct < 8; ++ct) {
            int col = ct * 16 + cl;
            union { unsigned long long q[2]; bf16x8 v; } bu;
            bu.q[0] = lds[(col << 5) | (g0 ^ cl)];
            bu.q[1] = lds[(col << 5) | (g1 ^ cl)];
            acc[ct] = __builtin_amdgcn_mfma_f32_16x16x32_bf16(af, bu.v, acc[ct], 0, 0, 0);
        }
    }
    // D layout: col = lane&15, row = (lane>>4)*4 + reg
    int rbase = base + kq * 4;
    #pragma unroll
    for (int ct = 0; ct < 8; ++ct) {
        #pragma unroll
        for (int r = 0; r < 4; ++r) {
            int row = rbase + r;
            if (row < N_V) X0[(size_t)row * 128 + ct * 16 + cl] = acc[ct][r];
        }
    }
}

// ---------------- CSR build: histogram / scan / fill ----------------
__global__ __launch_bounds__(256) void hist_k(const int* __restrict__ keys, int* __restrict__ cnt) {
    int e = blockIdx.x * 256 + threadIdx.x;
    if (e < NNZ_C) atomicAdd(&cnt[keys[e]], 1);
}

__global__ __launch_bounds__(256) void scan1_k(const int* __restrict__ cnt, int* __restrict__ off,
                                               int* __restrict__ bsum, int L) {
    __shared__ int s[256];
    int i = blockIdx.x * 256 + threadIdx.x;
    int v = (i < L) ? cnt[i] : 0;
    s[threadIdx.x] = v;
    __syncthreads();
    for (int d = 1; d < 256; d <<= 1) {
        int t = 0;
        if (threadIdx.x >= d) t = s[threadIdx.x - d];
        __syncthreads();
        if (threadIdx.x >= d) s[threadIdx.x] += t;
        __syncthreads();
    }
    if (i <= L) off[i] = s[threadIdx.x] - v;
    if (threadIdx.x == 255) bsum[blockIdx.x] = s[255];
}

__global__ __launch_bounds__(512) void scan2_k(int* __restrict__ bsum, int nb) {
    __shared__ int s[512];
    int t = threadIdx.x;
    int v = (t < nb) ? bsum[t] : 0;
    s[t] = v;
    __syncthreads();
    for (int d = 1; d < 512; d <<= 1) {
        int tv = 0;
        if (t >= d) tv = s[t - d];
        __syncthreads();
        if (t >= d) s[t] += tv;
        __syncthreads();
    }
    if (t < nb) bsum[t] = s[t] - v;
}

__global__ __launch_bounds__(256) void scan3_k(int* __restrict__ off, const int* __restrict__ bsum,
                                               int* __restrict__ cur, int L) {
    int i = blockIdx.x * 256 + threadIdx.x;
    if (i <= L) {
        int o = off[i] + bsum[i >> 8];
        off[i] = o;
        if (i < L) cur[i] = o;
    }
}

__global__ __launch_bounds__(256) void fill_k(const int* __restrict__ keys, const int* __restrict__ vals,
                                              int* __restrict__ cur, int* __restrict__ idx) {
    int e = blockIdx.x * 256 + threadIdx.x;
    if (e < NNZ_C) {
        int p = atomicAdd(&cur[keys[e]], 1);
        idx[p] = vals[e];
    }
}

// ---------------- edge aggregation (gather) + leaky attention logits ----------------
__global__ __launch_bounds__(256) void agg_gather_k(const float* __restrict__ X0,
                                                    const int* __restrict__ e_off,
                                                    const int* __restrict__ e_idx,
                                                    const float* __restrict__ att,
                                                    float* __restrict__ Xe,
                                                    float* __restrict__ alpha_l) {
    int wave = (int)((blockIdx.x * 256 + threadIdx.x) >> 6);
    int lane = threadIdx.x & 63;
    if (wave >= N_E) return;
    int beg = e_off[wave], end = e_off[wave + 1];
    float2 acc = {0.f, 0.f};
    for (int i = beg; i < end; ++i) {
        int v = e_idx[i];
        float2 x = ((const float2*)X0)[(size_t)v * 64 + lane];
        acc.x += x.x;
        acc.y += x.y;
    }
    float inv = 1.f / fmaxf((float)(end - beg), 1.f);
    acc.x *= inv; acc.y *= inv;
    ((float2*)Xe)[(size_t)wave * 64 + lane] = acc;
    float2 a2 = ((const float2*)att)[lane];
    float s = acc.x * a2.x + acc.y * a2.y;
    s += __shfl_xor(s, 1);
    s += __shfl_xor(s, 2);
    s += __shfl_xor(s, 4);
    if ((lane & 7) == 0) {
        s = (s >= 0.f) ? s : NEG * s;          // leaky applied once here
        alpha_l[wave * 8 + (lane >> 3)] = s;
    }
}

// ---------------- fused per-vertex softmax + attention-weighted gather ----------------
// one wave per vertex. Phase 1: online (max,sum) per head, 8 incidences in parallel.
// Phase 2: weighted accumulation, lane = channel pair, head = lane>>3.
__global__ __launch_bounds__(256) void out_fused_k(const float* __restrict__ Xe,
                                                   const float* __restrict__ alpha_l,
                                                   const int* __restrict__ v_off,
                                                   const int* __restrict__ v_idx,
                                                   float* __restrict__ out) {
    int wave = (int)((blockIdx.x * 256 + threadIdx.x) >> 6);
    int lane = threadIdx.x & 63;
    if (wave >= N_V) return;
    int beg = v_off[wave], end = v_off[wave + 1];

    const float SENT = -1e30f;                 // finite sentinel avoids inf-inf = NaN
    int h1 = lane & 7, s = lane >> 3;
    float m = SENT, d = 0.f;
    for (int i0 = beg; i0 < end; i0 += 8) {
        int i = i0 + s;
        float a = SENT;
        if (i < end) a = alpha_l[v_idx[i] * 8 + h1];
        float mn = fmaxf(m, a);
        d = d * __expf(m - mn) + ((i < end) ? __expf(a - mn) : 0.f);
        m = mn;
    }
    #pragma unroll
    for (int msk = 8; msk < 64; msk <<= 1) {
        float mo = __shfl_xor(m, msk);
        float dd = __shfl_xor(d, msk);
        float mn = fmaxf(m, mo);
        d = d * __expf(m - mn) + dd * __expf(mo - mn);
        m = mn;
    }
    int h = lane >> 3;
    float mh = __shfl(m, h);
    float dh = __shfl(d, h);
    float rd = 1.f / (dh + 1e-16f);

    float2 acc = {0.f, 0.f};
    for (int i = beg; i < end; ++i) {
        int ed = v_idx[i];
        float a = alpha_l[ed * 8 + h];
        float w = __expf(a - mh) * rd;
        float2 x = ((const float2*)Xe)[(size_t)ed * 64 + lane];
        acc.x += x.x * w;
        acc.y += x.y * w;
    }
    ((float2*)out)[(size_t)wave * 64 + lane] = acc;
}

extern "C" void kernel_launch(void* const* d_in, const int* in_sizes, int n_in,
                              void* d_out, int out_size, void* d_ws, size_t ws_size,
                              hipStream_t stream) {
    const float* X      = (const float*)d_in[0];
    const float* W      = (const float*)d_in[1];
    const float* att    = (const float*)d_in[2];
    const int*   vertex = (const int*)d_in[3];
    const int*   edges  = (const int*)d_in[4];
    float* out = (float*)d_out;

    // -------- workspace layout --------
    float* X0      = (float*)d_ws;                          // N*128 floats
    float* Xe      = X0 + (size_t)N_V * HC;                 // M*128 floats
    int*   e_off   = (int*)(Xe + (size_t)N_E * HC);         // M+1
    int*   ecnt    = e_off + (N_E + 1);                     // M
    int*   e_idx   = ecnt + N_E;                            // NNZ
    float* alpha_l = (float*)(e_idx + NNZ_C);               // M*8 (leaky'd logits)
    int*   bsum    = (int*)(alpha_l + (size_t)N_E * H_);    // 512
    unsigned short* Wt = (unsigned short*)(bsum + 512);     // 128*128 bf16 (32 KB)
    // overlay in X0's space (X0 dead after agg_gather_k):
    int*   v_off   = (int*)X0;                              // N+1
    int*   vcnt    = v_off + (N_V + 1);                     // N
    int*   v_idx   = vcnt + N_V;                            // NNZ

    const int nbE = (N_E + 1 + 255) / 256;
    const int nbV = (N_V + 1 + 255) / 256;

    // -------- edge CSR build --------
    hipMemsetAsync(ecnt, 0, sizeof(int) * N_E, stream);
    hist_k <<<NNZ_C / 256, 256, 0, stream>>>(edges, ecnt);
    scan1_k<<<nbE, 256, 0, stream>>>(ecnt, e_off, bsum, N_E);
    scan2_k<<<1, 512, 0, stream>>>(bsum, nbE);
    scan3_k<<<nbE, 256, 0, stream>>>(e_off, bsum, ecnt, N_E);
    fill_k <<<NNZ_C / 256, 256, 0, stream>>>(edges, vertex, ecnt, e_idx);

    // -------- GEMM (bf16 MFMA) + edge aggregation --------
    wt_k        <<<64, 256, 0, stream>>>(W, Wt);
    gemm_mfma_k <<<(N_V + 63) / 64, 256, 0, stream>>>(X, Wt, X0);
    agg_gather_k<<<(N_E * 64) / 256, 256, 0, stream>>>(X0, e_off, e_idx, att, Xe, alpha_l);

    // -------- vertex CSR build (overlays dead X0) --------
    hipMemsetAsync(vcnt, 0, sizeof(int) * N_V, stream);
    hist_k <<<NNZ_C / 256, 256, 0, stream>>>(vertex, vcnt);
    scan1_k<<<nbV, 256, 0, stream>>>(vcnt, v_off, bsum, N_V);
    scan2_k<<<1, 512, 0, stream>>>(bsum, nbV);
    scan3_k<<<nbV, 256, 0, stream>>>(v_off, bsum, vcnt, N_V);
    fill_k <<<NNZ_C / 256, 256, 0, stream>>>(vertex, edges, vcnt, v_idx);

    // -------- fused softmax + output gather --------
    out_fused_k<<<(N_V * 64) / 256, 256, 0, stream>>>(Xe, alpha_l, v_off, v_idx, out);
}